// Round 3
// baseline (170.251 us; speedup 1.0000x reference)
//
#include <hip/hip_runtime.h>
#include <math.h>

// Z = Q_F (D * (Q_F^T X Q_S)) Q_S^T  ==  per-column solve (I - g*lam_j*G) y_j = (X Q_S)_j ; Z = Y Q_S^T
// (I - aG)^-1 = prod_{j=0..4} (I + a^(2^j) G^(2^j))  (exact 31-term Neumann sum; rho <= 0.76)
// GEMMs: bf16 MFMA, hi/lo split (3 products) => fp32-level accuracy; split-K partial slabs, no atomics.

typedef short short8 __attribute__((ext_vector_type(8)));
typedef float floatx16 __attribute__((ext_vector_type(16)));

#define KSPLIT 16
#define KCHUNK 256  // 4096 / KSPLIT
constexpr int Mdim = 64;
constexpr int Ndim = 4096;
constexpr int SLAB = Mdim * Ndim;  // one split-K partial, 1 MB

__device__ inline ushort f2bf(float f) {
    uint u = __float_as_uint(f);
    u += 0x7fff + ((u >> 16) & 1);  // RNE
    return (ushort)(u >> 16);
}
__device__ inline float bf2f(ushort h) { return __uint_as_float(((uint)h) << 16); }

__device__ inline floatx16 mfma_bf16(short8 a, short8 b, floatx16 c) {
    return __builtin_amdgcn_mfma_f32_32x32x16_bf16(a, b, c, 0, 0, 0);
}

// LDS plane layout (bf16, 64x64 tile): elem (r,k) at r*64 + ((k>>3)^(r&7))*8 + (k&7).
struct SharedGemm { ushort Ah[4096], Al[4096], Bh[4096], Bl[4096]; };
struct SharedPrep { float Fraw[64 * 65]; ushort Ph[4096], Pl[4096]; float red[256]; };
union SharedU { SharedGemm g; SharedPrep p; };

// ---------------- prep body: G, G^2, G^4, G^8, G^16 (one block) -------------
__device__ void prep_body(SharedPrep& sp, const float* __restrict__ F, float* __restrict__ Gout) {
    const int t = threadIdx.x;
    const int l = t & 63, w = t >> 6;
    const int tm = w & 1, tn = w >> 1;
    const int am = tm * 32 + (l & 31);
    const int bn = tn * 32 + (l & 31);
    const int lk = l >> 5;

    for (int s = 0; s < 4; ++s) {
        int e = t + 256 * s;
        int r = e >> 4, q = (e & 15) * 4;
        float4 v = *(const float4*)&F[r * 64 + q];
        float fa[4] = {v.x, v.y, v.z, v.w};
        for (int i = 0; i < 4; ++i) sp.Fraw[r * 65 + q + i] = fa[i];
    }
    __syncthreads();
    {  // transpose into planes: P[c][k] = F[k][c]
        int c = t >> 2, kbase = (t & 3) * 16;
        ushort hh[16], ll[16];
#pragma unroll
        for (int kk = 0; kk < 16; ++kk) {
            float v = sp.Fraw[(kbase + kk) * 65 + c];
            ushort h = f2bf(v);
            hh[kk] = h;
            ll[kk] = f2bf(v - bf2f(h));
        }
#pragma unroll
        for (int g = 0; g < 2; ++g) {
            int gk = (kbase >> 3) + g;
            int idx = c * 64 + ((gk ^ (c & 7)) * 8);
#pragma unroll
            for (int u = 0; u < 8; ++u) { sp.Ph[idx + u] = hh[8 * g + u]; sp.Pl[idx + u] = ll[8 * g + u]; }
        }
    }
    __syncthreads();
    floatx16 acc;
    for (int i = 0; i < 16; ++i) acc[i] = 0.f;
    for (int s16 = 0; s16 < 4; ++s16) {
        int gk = 2 * s16 + lk;
        int ai = am * 64 + ((gk ^ (am & 7)) * 8);
        int bi = bn * 64 + ((gk ^ (bn & 7)) * 8);
        short8 ah = *(const short8*)&sp.Ph[ai];
        short8 al = *(const short8*)&sp.Pl[ai];
        short8 bh = *(const short8*)&sp.Ph[bi];
        short8 bl = *(const short8*)&sp.Pl[bi];
        acc = mfma_bf16(ah, bh, acc);
        acc = mfma_bf16(al, bh, acc);
        acc = mfma_bf16(ah, bl, acc);
    }
    float ss = 0.f;
    for (int r = 0; r < 16; ++r) ss += acc[r] * acc[r];
    sp.red[t] = ss;
    __syncthreads();
    for (int off = 128; off > 0; off >>= 1) {
        if (t < off) sp.red[t] += sp.red[t + off];
        __syncthreads();
    }
    const float inv = 1.0f / (sqrtf(sp.red[0]) + 1e-12f);
    for (int r = 0; r < 16; ++r) {
        int row = (r & 3) + 8 * (r >> 2) + 4 * lk + tm * 32;
        int col = tn * 32 + (l & 31);
        float v = acc[r] * inv;
        Gout[row * 64 + col] = v;
        ushort h = f2bf(v);
        int idx = row * 64 + (((col >> 3) ^ (row & 7)) * 8 + (col & 7));
        sp.Ph[idx] = h;
        sp.Pl[idx] = f2bf(v - bf2f(h));
    }
    for (int j = 1; j < 5; ++j) {
        __syncthreads();
        floatx16 a2;
        for (int i = 0; i < 16; ++i) a2[i] = 0.f;
        for (int s16 = 0; s16 < 4; ++s16) {
            int gk = 2 * s16 + lk;
            int ai = am * 64 + ((gk ^ (am & 7)) * 8);
            int bi = bn * 64 + ((gk ^ (bn & 7)) * 8);
            short8 ah = *(const short8*)&sp.Ph[ai];
            short8 al = *(const short8*)&sp.Pl[ai];
            short8 bh = *(const short8*)&sp.Ph[bi];
            short8 bl = *(const short8*)&sp.Pl[bi];
            a2 = mfma_bf16(ah, bh, a2);
            a2 = mfma_bf16(al, bh, a2);
            a2 = mfma_bf16(ah, bl, a2);
        }
        __syncthreads();
        for (int r = 0; r < 16; ++r) {
            int row = (r & 3) + 8 * (r >> 2) + 4 * lk + tm * 32;
            int col = tn * 32 + (l & 31);
            float v = a2[r];
            Gout[j * 4096 + row * 64 + col] = v;
            ushort h = f2bf(v);
            int idx = row * 64 + (((col >> 3) ^ (row & 7)) * 8 + (col & 7));
            sp.Ph[idx] = h;
            sp.Pl[idx] = f2bf(v - bf2f(h));
        }
    }
}

// ---------------- big GEMMs: P[slab] = A(64x4096) @ B-chunk ------------------
// TB=false: B[k][n] = Bm[k*4096+n]  (X @ Q_S);  TB=true: B[k][n] = Bm[n*4096+k]  (Y @ Q_S^T)
// DOPREP: block 0 runs prep_body instead (hidden under the gemm grid).
template <bool TB, bool DOPREP>
__global__ __launch_bounds__(256, 4) void gemm_kernel(const float* __restrict__ A,
                                                      const float* __restrict__ Bm,
                                                      float* __restrict__ C,
                                                      const float* __restrict__ F,
                                                      float* __restrict__ Gp) {
    __shared__ SharedU sh;
    const int bid = blockIdx.x;
    if (DOPREP) {
        if (bid == 0) { prep_body(sh.p, F, Gp); return; }
    }
    const int b = DOPREP ? bid - 1 : bid;
    const int n0 = (b & 63) * 64;
    const int kb = (b >> 6) * KCHUNK;
    const int t = threadIdx.x;
    const int l = t & 63, w = t >> 6;
    const int tm = w & 1, tn = w >> 1;
    const int am = tm * 32 + (l & 31);
    const int bn = tn * 32 + (l & 31);
    const int lk = l >> 5;
    const int sr = t >> 2, sj = t & 3;          // row-staging map
    const int nq = t & 15, kr2 = 2 * (t >> 4);  // transpose-staging map

    floatx16 acc;
    for (int i = 0; i < 16; ++i) acc[i] = 0.f;

    for (int step = 0; step < KCHUNK / 64; ++step) {
        const int k0 = kb + step * 64;
        float4 av[4], bv[4], bva[2], bvb[2];
        for (int s = 0; s < 4; ++s)
            av[s] = *(const float4*)&A[sr * 4096 + k0 + 4 * sj + 16 * s];
        if (TB) {
            for (int s = 0; s < 4; ++s)
                bv[s] = *(const float4*)&Bm[(size_t)(n0 + sr) * 4096 + k0 + 4 * sj + 16 * s];
        } else {
            for (int s = 0; s < 2; ++s) {
                bva[s] = *(const float4*)&Bm[(size_t)(k0 + kr2 + 32 * s) * 4096 + n0 + 4 * nq];
                bvb[s] = *(const float4*)&Bm[(size_t)(k0 + kr2 + 1 + 32 * s) * 4096 + n0 + 4 * nq];
            }
        }
        __syncthreads();  // previous step's frag reads done
        for (int s = 0; s < 4; ++s) {
            int off = 4 * sj + 16 * s;
            int idx = sr * 64 + (((off >> 3) ^ (sr & 7)) * 8 + (off & 7));
            float fa[4] = {av[s].x, av[s].y, av[s].z, av[s].w};
            ushort4 h4, l4;
            ushort* hp = (ushort*)&h4; ushort* lp = (ushort*)&l4;
            for (int i = 0; i < 4; ++i) {
                ushort h = f2bf(fa[i]);
                hp[i] = h; lp[i] = f2bf(fa[i] - bf2f(h));
            }
            *(ushort4*)&sh.g.Ah[idx] = h4;
            *(ushort4*)&sh.g.Al[idx] = l4;
        }
        if (TB) {
            for (int s = 0; s < 4; ++s) {
                int off = 4 * sj + 16 * s;
                int idx = sr * 64 + (((off >> 3) ^ (sr & 7)) * 8 + (off & 7));
                float fb[4] = {bv[s].x, bv[s].y, bv[s].z, bv[s].w};
                ushort4 h4, l4;
                ushort* hp = (ushort*)&h4; ushort* lp = (ushort*)&l4;
                for (int i = 0; i < 4; ++i) {
                    ushort h = f2bf(fb[i]);
                    hp[i] = h; lp[i] = f2bf(fb[i] - bf2f(h));
                }
                *(ushort4*)&sh.g.Bh[idx] = h4;
                *(ushort4*)&sh.g.Bl[idx] = l4;
            }
        } else {
            for (int s = 0; s < 2; ++s) {
                int k = kr2 + 32 * s;
                float fa[4] = {bva[s].x, bva[s].y, bva[s].z, bva[s].w};
                float fb[4] = {bvb[s].x, bvb[s].y, bvb[s].z, bvb[s].w};
                for (int i = 0; i < 4; ++i) {
                    int n = 4 * nq + i;
                    int idx = n * 64 + (((k >> 3) ^ (n & 7)) * 8 + (k & 7));
                    ushort2 hp2, lp2;
                    hp2.x = f2bf(fa[i]); hp2.y = f2bf(fb[i]);
                    lp2.x = f2bf(fa[i] - bf2f(hp2.x));
                    lp2.y = f2bf(fb[i] - bf2f(hp2.y));
                    *(ushort2*)&sh.g.Bh[idx] = hp2;
                    *(ushort2*)&sh.g.Bl[idx] = lp2;
                }
            }
        }
        __syncthreads();
#pragma unroll
        for (int s16 = 0; s16 < 4; ++s16) {
            int gk = 2 * s16 + lk;
            int ai = am * 64 + ((gk ^ (am & 7)) * 8);
            int bi = bn * 64 + ((gk ^ (bn & 7)) * 8);
            short8 ah = *(const short8*)&sh.g.Ah[ai];
            short8 al = *(const short8*)&sh.g.Al[ai];
            short8 bh = *(const short8*)&sh.g.Bh[bi];
            short8 bl = *(const short8*)&sh.g.Bl[bi];
            acc = mfma_bf16(ah, bh, acc);
            acc = mfma_bf16(al, bh, acc);
            acc = mfma_bf16(ah, bl, acc);
        }
    }
    float* Cslab = C + (size_t)(b >> 6) * SLAB;
    const int colg = n0 + tn * 32 + (l & 31);
#pragma unroll
    for (int r = 0; r < 16; ++r) {
        int row = (r & 3) + 8 * (r >> 2) + 4 * lk + tm * 32;
        Cslab[row * 4096 + colg] = acc[r];
    }
}

// ---------------- solve: sum 16 slabs, then T += a^(2^j) * (G_j @ T) --------
__global__ __launch_bounds__(256) void solve_kernel(const float* __restrict__ W,
                                                    const float* __restrict__ Gp,
                                                    const float* __restrict__ lam,
                                                    const float* __restrict__ gammap,
                                                    float* __restrict__ Y) {
    __shared__ float Gs[64][68];
    __shared__ float T[64][17];
    const int t = threadIdx.x;
    const int c0 = blockIdx.x * 16;
    for (int e = t; e < 1024; e += 256) {
        const int r = e >> 4, c = c0 + (e & 15);
        float s = 0.f;
#pragma unroll
        for (int bsl = 0; bsl < KSPLIT; ++bsl) s += W[bsl * SLAB + r * 4096 + c];
        T[r][e & 15] = s;
    }
    const int tx = t & 15;
    const int r4 = (t >> 4) * 4;
    const float a = gammap[0] * lam[c0 + tx];
    float s = a;
    for (int j = 0; j < 5; ++j) {
        __syncthreads();
        for (int e = t; e < 4096; e += 256) Gs[e >> 6][e & 63] = Gp[j * 4096 + e];
        __syncthreads();
        float u0 = 0.f, u1 = 0.f, u2 = 0.f, u3 = 0.f;
#pragma unroll 8
        for (int k = 0; k < 64; ++k) {
            const float tv = T[k][tx];
            const float4 g = *(const float4*)&Gs[k][r4];
            u0 += g.x * tv; u1 += g.y * tv; u2 += g.z * tv; u3 += g.w * tv;
        }
        __syncthreads();
        T[r4 + 0][tx] += s * u0;
        T[r4 + 1][tx] += s * u1;
        T[r4 + 2][tx] += s * u2;
        T[r4 + 3][tx] += s * u3;
        s = s * s;
    }
    __syncthreads();
    for (int e = t; e < 1024; e += 256)
        Y[(e >> 4) * 4096 + c0 + (e & 15)] = T[e >> 4][e & 15];
}

// ---------------- reduce: Z = sum of 16 partial slabs ------------------------
__global__ __launch_bounds__(256) void reduce_kernel(const float* __restrict__ P,
                                                     float* __restrict__ Z) {
    const int i = blockIdx.x * 256 + threadIdx.x;  // float4 index, 65536 total
    float4 a = {0.f, 0.f, 0.f, 0.f};
#pragma unroll
    for (int bsl = 0; bsl < KSPLIT; ++bsl) {
        float4 v = *(const float4*)&P[(size_t)bsl * SLAB + i * 4];
        a.x += v.x; a.y += v.y; a.z += v.z; a.w += v.w;
    }
    *(float4*)&Z[i * 4] = a;
}

extern "C" void kernel_launch(void* const* d_in, const int* in_sizes, int n_in,
                              void* d_out, int out_size, void* d_ws, size_t ws_size,
                              hipStream_t stream) {
    const float* X     = (const float*)d_in[0];
    const float* F     = (const float*)d_in[1];
    const float* Qs    = (const float*)d_in[2];
    const float* lam   = (const float*)d_in[3];
    const float* gamma = (const float*)d_in[4];
    float* Z = (float*)d_out;

    float* P1 = (float*)d_ws;               // 16 slabs, 16 MB
    float* P2 = P1 + (size_t)KSPLIT * SLAB; // 16 slabs, 16 MB
    float* Gp = P2 + (size_t)KSPLIT * SLAB; // 5 * 64*64
    float* Y  = Gp + 5 * 4096;              // 1 MB

    gemm_kernel<false, true><<<64 * KSPLIT + 1, 256, 0, stream>>>(X, Qs, P1, F, Gp);
    solve_kernel<<<Ndim / 16, 256, 0, stream>>>(P1, Gp, lam, gamma, Y);
    gemm_kernel<true, false><<<64 * KSPLIT, 256, 0, stream>>>(Y, Qs, P2, nullptr, nullptr);
    reduce_kernel<<<256, 256, 0, stream>>>(P2, Z);
}

// Round 4
// 169.245 us; speedup vs baseline: 1.0059x; 1.0059x over previous
//
#include <hip/hip_runtime.h>
#include <math.h>

// Z = Q_F (D * (Q_F^T X Q_S)) Q_S^T  ==  per-column solve (I - g*lam_j*G) y_j = (X Q_S)_j ; Z = Y Q_S^T
// (I - aG)^-1 = prod_{j=0..4} (I + a^(2^j) G^(2^j))  (exact 31-term Neumann sum; rho <= 0.76)
// GEMMs: bf16 MFMA, hi/lo split (3 products) => fp32-level accuracy; split-K + fp32 atomics (1 MB target, L2-resident).

typedef short short8 __attribute__((ext_vector_type(8)));
typedef float floatx16 __attribute__((ext_vector_type(16)));

#define KSPLIT 8
#define KCHUNK 512  // 4096 / KSPLIT
constexpr int Mdim = 64;
constexpr int Ndim = 4096;

__device__ inline ushort f2bf(float f) {
    uint u = __float_as_uint(f);
    u += 0x7fff + ((u >> 16) & 1);  // RNE
    return (ushort)(u >> 16);
}
__device__ inline float bf2f(ushort h) { return __uint_as_float(((uint)h) << 16); }

__device__ inline floatx16 mfma_bf16(short8 a, short8 b, floatx16 c) {
    return __builtin_amdgcn_mfma_f32_32x32x16_bf16(a, b, c, 0, 0, 0);
}

// LDS plane layout (bf16, 64x64 tile): elem (r,k) at r*64 + ((k>>3)^(r&7))*8 + (k&7).
struct SharedGemm { ushort Ah[4096], Al[4096], Bh[4096], Bl[4096]; };
struct SharedPrep { float Fraw[64 * 65]; ushort Ph[4096], Pl[4096]; float red[256]; };
union SharedU { SharedGemm g; SharedPrep p; };

// ---------------- init: zero W (ws) and Z (d_out) ----------------------------
__global__ __launch_bounds__(256) void init_kernel(float* __restrict__ W, float* __restrict__ Z) {
    const int i = blockIdx.x * 256 + threadIdx.x;  // 512 blocks * 256 t * 4 floats = 2 MB
    float4 z = {0.f, 0.f, 0.f, 0.f};
    if (i < 65536) *(float4*)&W[i * 4] = z;
    else *(float4*)&Z[(i - 65536) * 4] = z;
}

// ---------------- prep body: G, G^2, G^4, G^8, G^16 (one block) -------------
__device__ void prep_body(SharedPrep& sp, const float* __restrict__ F, float* __restrict__ Gout) {
    const int t = threadIdx.x;
    const int l = t & 63, w = t >> 6;
    const int tm = w & 1, tn = w >> 1;
    const int am = tm * 32 + (l & 31);
    const int bn = tn * 32 + (l & 31);
    const int lk = l >> 5;

    for (int s = 0; s < 4; ++s) {
        int e = t + 256 * s;
        int r = e >> 4, q = (e & 15) * 4;
        float4 v = *(const float4*)&F[r * 64 + q];
        float fa[4] = {v.x, v.y, v.z, v.w};
        for (int i = 0; i < 4; ++i) sp.Fraw[r * 65 + q + i] = fa[i];
    }
    __syncthreads();
    {  // transpose into planes: P[c][k] = F[k][c]
        int c = t >> 2, kbase = (t & 3) * 16;
        ushort hh[16], ll[16];
#pragma unroll
        for (int kk = 0; kk < 16; ++kk) {
            float v = sp.Fraw[(kbase + kk) * 65 + c];
            ushort h = f2bf(v);
            hh[kk] = h;
            ll[kk] = f2bf(v - bf2f(h));
        }
#pragma unroll
        for (int g = 0; g < 2; ++g) {
            int gk = (kbase >> 3) + g;
            int idx = c * 64 + ((gk ^ (c & 7)) * 8);
#pragma unroll
            for (int u = 0; u < 8; ++u) { sp.Ph[idx + u] = hh[8 * g + u]; sp.Pl[idx + u] = ll[8 * g + u]; }
        }
    }
    __syncthreads();
    floatx16 acc;
    for (int i = 0; i < 16; ++i) acc[i] = 0.f;
    for (int s16 = 0; s16 < 4; ++s16) {
        int gk = 2 * s16 + lk;
        int ai = am * 64 + ((gk ^ (am & 7)) * 8);
        int bi = bn * 64 + ((gk ^ (bn & 7)) * 8);
        short8 ah = *(const short8*)&sp.Ph[ai];
        short8 al = *(const short8*)&sp.Pl[ai];
        short8 bh = *(const short8*)&sp.Ph[bi];
        short8 bl = *(const short8*)&sp.Pl[bi];
        acc = mfma_bf16(ah, bh, acc);
        acc = mfma_bf16(al, bh, acc);
        acc = mfma_bf16(ah, bl, acc);
    }
    float ss = 0.f;
    for (int r = 0; r < 16; ++r) ss += acc[r] * acc[r];
    sp.red[t] = ss;
    __syncthreads();
    for (int off = 128; off > 0; off >>= 1) {
        if (t < off) sp.red[t] += sp.red[t + off];
        __syncthreads();
    }
    const float inv = 1.0f / (sqrtf(sp.red[0]) + 1e-12f);
    for (int r = 0; r < 16; ++r) {
        int row = (r & 3) + 8 * (r >> 2) + 4 * lk + tm * 32;
        int col = tn * 32 + (l & 31);
        float v = acc[r] * inv;
        Gout[row * 64 + col] = v;
        ushort h = f2bf(v);
        int idx = row * 64 + (((col >> 3) ^ (row & 7)) * 8 + (col & 7));
        sp.Ph[idx] = h;
        sp.Pl[idx] = f2bf(v - bf2f(h));
    }
    for (int j = 1; j < 5; ++j) {
        __syncthreads();
        floatx16 a2;
        for (int i = 0; i < 16; ++i) a2[i] = 0.f;
        for (int s16 = 0; s16 < 4; ++s16) {
            int gk = 2 * s16 + lk;
            int ai = am * 64 + ((gk ^ (am & 7)) * 8);
            int bi = bn * 64 + ((gk ^ (bn & 7)) * 8);
            short8 ah = *(const short8*)&sp.Ph[ai];
            short8 al = *(const short8*)&sp.Pl[ai];
            short8 bh = *(const short8*)&sp.Ph[bi];
            short8 bl = *(const short8*)&sp.Pl[bi];
            a2 = mfma_bf16(ah, bh, a2);
            a2 = mfma_bf16(al, bh, a2);
            a2 = mfma_bf16(ah, bl, a2);
        }
        __syncthreads();
        for (int r = 0; r < 16; ++r) {
            int row = (r & 3) + 8 * (r >> 2) + 4 * lk + tm * 32;
            int col = tn * 32 + (l & 31);
            float v = a2[r];
            Gout[j * 4096 + row * 64 + col] = v;
            ushort h = f2bf(v);
            int idx = row * 64 + (((col >> 3) ^ (row & 7)) * 8 + (col & 7));
            sp.Ph[idx] = h;
            sp.Pl[idx] = f2bf(v - bf2f(h));
        }
    }
}

// ---------------- big GEMMs: C += A(64x4096) @ B-chunk (fp32 atomics) -------
// TB=false: B[k][n] = Bm[k*4096+n]  (X @ Q_S);  TB=true: B[k][n] = Bm[n*4096+k]  (Y @ Q_S^T)
// DOPREP: block 0 runs prep_body instead (hidden under the gemm grid).
template <bool TB, bool DOPREP>
__global__ __launch_bounds__(256, 4) void gemm_kernel(const float* __restrict__ A,
                                                      const float* __restrict__ Bm,
                                                      float* __restrict__ C,
                                                      const float* __restrict__ F,
                                                      float* __restrict__ Gp) {
    __shared__ SharedU sh;
    const int bid = blockIdx.x;
    if (DOPREP) {
        if (bid == 0) { prep_body(sh.p, F, Gp); return; }
    }
    const int b = DOPREP ? bid - 1 : bid;
    const int n0 = (b & 63) * 64;
    const int kb = (b >> 6) * KCHUNK;
    const int t = threadIdx.x;
    const int l = t & 63, w = t >> 6;
    const int tm = w & 1, tn = w >> 1;
    const int am = tm * 32 + (l & 31);
    const int bn = tn * 32 + (l & 31);
    const int lk = l >> 5;
    const int sr = t >> 2, sj = t & 3;          // row-staging map
    const int nq = t & 15, kr2 = 2 * (t >> 4);  // transpose-staging map

    floatx16 acc;
    for (int i = 0; i < 16; ++i) acc[i] = 0.f;

    for (int step = 0; step < KCHUNK / 64; ++step) {
        const int k0 = kb + step * 64;
        float4 av[4], bv[4], bva[2], bvb[2];
        for (int s = 0; s < 4; ++s)
            av[s] = *(const float4*)&A[sr * 4096 + k0 + 4 * sj + 16 * s];
        if (TB) {
            for (int s = 0; s < 4; ++s)
                bv[s] = *(const float4*)&Bm[(size_t)(n0 + sr) * 4096 + k0 + 4 * sj + 16 * s];
        } else {
            for (int s = 0; s < 2; ++s) {
                bva[s] = *(const float4*)&Bm[(size_t)(k0 + kr2 + 32 * s) * 4096 + n0 + 4 * nq];
                bvb[s] = *(const float4*)&Bm[(size_t)(k0 + kr2 + 1 + 32 * s) * 4096 + n0 + 4 * nq];
            }
        }
        __syncthreads();  // previous step's frag reads done
        for (int s = 0; s < 4; ++s) {
            int off = 4 * sj + 16 * s;
            int idx = sr * 64 + (((off >> 3) ^ (sr & 7)) * 8 + (off & 7));
            float fa[4] = {av[s].x, av[s].y, av[s].z, av[s].w};
            ushort4 h4, l4;
            ushort* hp = (ushort*)&h4; ushort* lp = (ushort*)&l4;
            for (int i = 0; i < 4; ++i) {
                ushort h = f2bf(fa[i]);
                hp[i] = h; lp[i] = f2bf(fa[i] - bf2f(h));
            }
            *(ushort4*)&sh.g.Ah[idx] = h4;
            *(ushort4*)&sh.g.Al[idx] = l4;
        }
        if (TB) {
            for (int s = 0; s < 4; ++s) {
                int off = 4 * sj + 16 * s;
                int idx = sr * 64 + (((off >> 3) ^ (sr & 7)) * 8 + (off & 7));
                float fb[4] = {bv[s].x, bv[s].y, bv[s].z, bv[s].w};
                ushort4 h4, l4;
                ushort* hp = (ushort*)&h4; ushort* lp = (ushort*)&l4;
                for (int i = 0; i < 4; ++i) {
                    ushort h = f2bf(fb[i]);
                    hp[i] = h; lp[i] = f2bf(fb[i] - bf2f(h));
                }
                *(ushort4*)&sh.g.Bh[idx] = h4;
                *(ushort4*)&sh.g.Bl[idx] = l4;
            }
        } else {
            for (int s = 0; s < 2; ++s) {
                int k = kr2 + 32 * s;
                float fa[4] = {bva[s].x, bva[s].y, bva[s].z, bva[s].w};
                float fb[4] = {bvb[s].x, bvb[s].y, bvb[s].z, bvb[s].w};
                for (int i = 0; i < 4; ++i) {
                    int n = 4 * nq + i;
                    int idx = n * 64 + (((k >> 3) ^ (n & 7)) * 8 + (k & 7));
                    ushort2 hp2, lp2;
                    hp2.x = f2bf(fa[i]); hp2.y = f2bf(fb[i]);
                    lp2.x = f2bf(fa[i] - bf2f(hp2.x));
                    lp2.y = f2bf(fb[i] - bf2f(hp2.y));
                    *(ushort2*)&sh.g.Bh[idx] = hp2;
                    *(ushort2*)&sh.g.Bl[idx] = lp2;
                }
            }
        }
        __syncthreads();
#pragma unroll
        for (int s16 = 0; s16 < 4; ++s16) {
            int gk = 2 * s16 + lk;
            int ai = am * 64 + ((gk ^ (am & 7)) * 8);
            int bi = bn * 64 + ((gk ^ (bn & 7)) * 8);
            short8 ah = *(const short8*)&sh.g.Ah[ai];
            short8 al = *(const short8*)&sh.g.Al[ai];
            short8 bh = *(const short8*)&sh.g.Bh[bi];
            short8 bl = *(const short8*)&sh.g.Bl[bi];
            acc = mfma_bf16(ah, bh, acc);
            acc = mfma_bf16(al, bh, acc);
            acc = mfma_bf16(ah, bl, acc);
        }
    }
    const int colg = n0 + tn * 32 + (l & 31);
#pragma unroll
    for (int r = 0; r < 16; ++r) {
        int row = (r & 3) + 8 * (r >> 2) + 4 * lk + tm * 32;
        atomicAdd(&C[row * 4096 + colg], acc[r]);
    }
}

// ---------------- solve: T += a^(2^j) * (G_j @ T), j=0..4 -------------------
__global__ __launch_bounds__(256) void solve_kernel(const float* __restrict__ W,
                                                    const float* __restrict__ Gp,
                                                    const float* __restrict__ lam,
                                                    const float* __restrict__ gammap,
                                                    float* __restrict__ Y) {
    __shared__ float Gs[64][68];
    __shared__ float T[64][17];
    const int t = threadIdx.x;
    const int c0 = blockIdx.x * 16;
    for (int e = t; e < 1024; e += 256)
        T[e >> 4][e & 15] = W[(e >> 4) * 4096 + c0 + (e & 15)];
    const int tx = t & 15;
    const int r4 = (t >> 4) * 4;
    const float a = gammap[0] * lam[c0 + tx];
    float s = a;
    for (int j = 0; j < 5; ++j) {
        __syncthreads();
        for (int e = t; e < 4096; e += 256) Gs[e >> 6][e & 63] = Gp[j * 4096 + e];
        __syncthreads();
        float u0 = 0.f, u1 = 0.f, u2 = 0.f, u3 = 0.f;
#pragma unroll 8
        for (int k = 0; k < 64; ++k) {
            const float tv = T[k][tx];
            const float4 g = *(const float4*)&Gs[k][r4];
            u0 += g.x * tv; u1 += g.y * tv; u2 += g.z * tv; u3 += g.w * tv;
        }
        __syncthreads();
        T[r4 + 0][tx] += s * u0;
        T[r4 + 1][tx] += s * u1;
        T[r4 + 2][tx] += s * u2;
        T[r4 + 3][tx] += s * u3;
        s = s * s;
    }
    __syncthreads();
    for (int e = t; e < 1024; e += 256)
        Y[(e >> 4) * 4096 + c0 + (e & 15)] = T[e >> 4][e & 15];
}

extern "C" void kernel_launch(void* const* d_in, const int* in_sizes, int n_in,
                              void* d_out, int out_size, void* d_ws, size_t ws_size,
                              hipStream_t stream) {
    const float* X     = (const float*)d_in[0];
    const float* F     = (const float*)d_in[1];
    const float* Qs    = (const float*)d_in[2];
    const float* lam   = (const float*)d_in[3];
    const float* gamma = (const float*)d_in[4];
    float* Z = (float*)d_out;

    float* W  = (float*)d_ws;   // 1 MB
    float* Y  = W + Mdim * Ndim;
    float* Gp = Y + Mdim * Ndim;

    init_kernel<<<512, 256, 0, stream>>>(W, Z);
    gemm_kernel<false, true><<<64 * KSPLIT + 1, 256, 0, stream>>>(X, Qs, W, F, Gp);
    solve_kernel<<<Ndim / 16, 256, 0, stream>>>(W, Gp, lam, gamma, Y);
    gemm_kernel<true, false><<<64 * KSPLIT, 256, 0, stream>>>(Y, Qs, Z, nullptr, nullptr);
}

// Round 5
// 158.145 us; speedup vs baseline: 1.0765x; 1.0702x over previous
//
#include <hip/hip_runtime.h>
#include <math.h>

// Z = Q_F (D * (Q_F^T X Q_S)) Q_S^T  ==  per-column solve (I - g*lam_j*G) y_j = (X Q_S)_j ; Z = Y Q_S^T
// (I - aG)^-1 = prod_{j=0..4} (I + a^(2^j) G^(2^j))  (exact 31-term Neumann sum; rho <= 0.76)
// GEMMs: bf16 MFMA, A = hi+lo split (2 products), B = bf16 (2^-9 rel, OK vs 0.099 threshold);
// split-K=16 + fp32 atomics; register-prefetch pipeline on the B (Q_S) HBM stream.

typedef short short8 __attribute__((ext_vector_type(8)));
typedef float floatx16 __attribute__((ext_vector_type(16)));

#define KSPLIT 16
#define KCHUNK 256  // 4096 / KSPLIT, 4 steps of 64
constexpr int Mdim = 64;
constexpr int Ndim = 4096;

__device__ inline ushort f2bf(float f) {
    uint u = __float_as_uint(f);
    u += 0x7fff + ((u >> 16) & 1);  // RNE
    return (ushort)(u >> 16);
}
__device__ inline float bf2f(ushort h) { return __uint_as_float(((uint)h) << 16); }

__device__ inline floatx16 mfma_bf16(short8 a, short8 b, floatx16 c) {
    return __builtin_amdgcn_mfma_f32_32x32x16_bf16(a, b, c, 0, 0, 0);
}

// LDS plane layout (bf16, 64x64 tile): elem (r,k) at r*64 + ((k>>3)^(r&7))*8 + (k&7).
struct SharedGemm { ushort Ah[4096], Al[4096], Bh[4096]; };
struct SharedPrep { float Fraw[64 * 65]; ushort Ph[4096], Pl[4096]; float red[256]; };
union SharedU { SharedGemm g; SharedPrep p; };

// ---------------- init: zero W (ws) and Z (d_out) ----------------------------
__global__ __launch_bounds__(256) void init_kernel(float* __restrict__ W, float* __restrict__ Z) {
    const int i = blockIdx.x * 256 + threadIdx.x;
    float4 z = {0.f, 0.f, 0.f, 0.f};
    if (i < 65536) *(float4*)&W[i * 4] = z;
    else *(float4*)&Z[(i - 65536) * 4] = z;
}

// ---------------- prep body: G, G^2, G^4, G^8, G^16 (one block) -------------
__device__ void prep_body(SharedPrep& sp, const float* __restrict__ F, float* __restrict__ Gout) {
    const int t = threadIdx.x;
    const int l = t & 63, w = t >> 6;
    const int tm = w & 1, tn = w >> 1;
    const int am = tm * 32 + (l & 31);
    const int bn = tn * 32 + (l & 31);
    const int lk = l >> 5;

    for (int s = 0; s < 4; ++s) {
        int e = t + 256 * s;
        int r = e >> 4, q = (e & 15) * 4;
        float4 v = *(const float4*)&F[r * 64 + q];
        float fa[4] = {v.x, v.y, v.z, v.w};
        for (int i = 0; i < 4; ++i) sp.Fraw[r * 65 + q + i] = fa[i];
    }
    __syncthreads();
    {  // transpose into planes: P[c][k] = F[k][c]
        int c = t >> 2, kbase = (t & 3) * 16;
        ushort hh[16], ll[16];
#pragma unroll
        for (int kk = 0; kk < 16; ++kk) {
            float v = sp.Fraw[(kbase + kk) * 65 + c];
            ushort h = f2bf(v);
            hh[kk] = h;
            ll[kk] = f2bf(v - bf2f(h));
        }
#pragma unroll
        for (int g = 0; g < 2; ++g) {
            int gk = (kbase >> 3) + g;
            int idx = c * 64 + ((gk ^ (c & 7)) * 8);
#pragma unroll
            for (int u = 0; u < 8; ++u) { sp.Ph[idx + u] = hh[8 * g + u]; sp.Pl[idx + u] = ll[8 * g + u]; }
        }
    }
    __syncthreads();
    floatx16 acc;
    for (int i = 0; i < 16; ++i) acc[i] = 0.f;
    for (int s16 = 0; s16 < 4; ++s16) {
        int gk = 2 * s16 + lk;
        int ai = am * 64 + ((gk ^ (am & 7)) * 8);
        int bi = bn * 64 + ((gk ^ (bn & 7)) * 8);
        short8 ah = *(const short8*)&sp.Ph[ai];
        short8 al = *(const short8*)&sp.Pl[ai];
        short8 bh = *(const short8*)&sp.Ph[bi];
        short8 bl = *(const short8*)&sp.Pl[bi];
        acc = mfma_bf16(ah, bh, acc);
        acc = mfma_bf16(al, bh, acc);
        acc = mfma_bf16(ah, bl, acc);
    }
    float ss = 0.f;
    for (int r = 0; r < 16; ++r) ss += acc[r] * acc[r];
    sp.red[t] = ss;
    __syncthreads();
    for (int off = 128; off > 0; off >>= 1) {
        if (t < off) sp.red[t] += sp.red[t + off];
        __syncthreads();
    }
    const float inv = 1.0f / (sqrtf(sp.red[0]) + 1e-12f);
    for (int r = 0; r < 16; ++r) {
        int row = (r & 3) + 8 * (r >> 2) + 4 * lk + tm * 32;
        int col = tn * 32 + (l & 31);
        float v = acc[r] * inv;
        Gout[row * 64 + col] = v;
        ushort h = f2bf(v);
        int idx = row * 64 + (((col >> 3) ^ (row & 7)) * 8 + (col & 7));
        sp.Ph[idx] = h;
        sp.Pl[idx] = f2bf(v - bf2f(h));
    }
    for (int j = 1; j < 5; ++j) {
        __syncthreads();
        floatx16 a2;
        for (int i = 0; i < 16; ++i) a2[i] = 0.f;
        for (int s16 = 0; s16 < 4; ++s16) {
            int gk = 2 * s16 + lk;
            int ai = am * 64 + ((gk ^ (am & 7)) * 8);
            int bi = bn * 64 + ((gk ^ (bn & 7)) * 8);
            short8 ah = *(const short8*)&sp.Ph[ai];
            short8 al = *(const short8*)&sp.Pl[ai];
            short8 bh = *(const short8*)&sp.Ph[bi];
            short8 bl = *(const short8*)&sp.Pl[bi];
            a2 = mfma_bf16(ah, bh, a2);
            a2 = mfma_bf16(al, bh, a2);
            a2 = mfma_bf16(ah, bl, a2);
        }
        __syncthreads();
        for (int r = 0; r < 16; ++r) {
            int row = (r & 3) + 8 * (r >> 2) + 4 * lk + tm * 32;
            int col = tn * 32 + (l & 31);
            float v = a2[r];
            Gout[j * 4096 + row * 64 + col] = v;
            ushort h = f2bf(v);
            int idx = row * 64 + (((col >> 3) ^ (row & 7)) * 8 + (col & 7));
            sp.Ph[idx] = h;
            sp.Pl[idx] = f2bf(v - bf2f(h));
        }
    }
}

// ---------------- big GEMMs: C += A(64x4096) @ B-chunk (fp32 atomics) -------
// TB=false: B[k][n] = Bm[k*4096+n]  (X @ Q_S);  TB=true: B[k][n] = Bm[n*4096+k]  (Y @ Q_S^T)
// B stream register-prefetched one step ahead; A (L2-hot) loaded in-step.
template <bool TB, bool DOPREP>
__global__ __launch_bounds__(256, 4) void gemm_kernel(const float* __restrict__ A,
                                                      const float* __restrict__ Bm,
                                                      float* __restrict__ C,
                                                      const float* __restrict__ F,
                                                      float* __restrict__ Gp) {
    __shared__ SharedU sh;
    const int bid = blockIdx.x;
    if (DOPREP) {
        if (bid == 0) { prep_body(sh.p, F, Gp); return; }
    }
    const int b = DOPREP ? bid - 1 : bid;
    const int n0 = (b & 63) * 64;
    const int kb = (b >> 6) * KCHUNK;
    const int t = threadIdx.x;
    const int l = t & 63, w = t >> 6;
    const int tm = w & 1, tn = w >> 1;
    const int am = tm * 32 + (l & 31);
    const int bn = tn * 32 + (l & 31);
    const int lk = l >> 5;
    const int sr = t >> 2, sj = t & 3;          // row-staging map
    const int nq = t & 15, kr2 = 2 * (t >> 4);  // transpose-staging map

    floatx16 acc;
    for (int i = 0; i < 16; ++i) acc[i] = 0.f;

    float4 bbuf[2][4];
    // preload B step 0
    if (TB) {
#pragma unroll
        for (int s = 0; s < 4; ++s)
            bbuf[0][s] = *(const float4*)&Bm[(size_t)(n0 + sr) * 4096 + kb + 4 * sj + 16 * s];
    } else {
#pragma unroll
        for (int s = 0; s < 2; ++s) {
            bbuf[0][2 * s + 0] = *(const float4*)&Bm[(size_t)(kb + kr2 + 32 * s) * 4096 + n0 + 4 * nq];
            bbuf[0][2 * s + 1] = *(const float4*)&Bm[(size_t)(kb + kr2 + 1 + 32 * s) * 4096 + n0 + 4 * nq];
        }
    }

#pragma unroll
    for (int step = 0; step < KCHUNK / 64; ++step) {
        const int k0 = kb + step * 64;
        const int cur = step & 1, nxt = cur ^ 1;
        // A loads for this step (L2-hot, short latency)
        float4 av[4];
#pragma unroll
        for (int s = 0; s < 4; ++s)
            av[s] = *(const float4*)&A[sr * 4096 + k0 + 4 * sj + 16 * s];
        __syncthreads();  // previous step's frag reads done
        // prefetch B for next step (HBM latency overlaps staging + MFMA)
        if (step + 1 < KCHUNK / 64) {
            const int k1 = k0 + 64;
            if (TB) {
#pragma unroll
                for (int s = 0; s < 4; ++s)
                    bbuf[nxt][s] = *(const float4*)&Bm[(size_t)(n0 + sr) * 4096 + k1 + 4 * sj + 16 * s];
            } else {
#pragma unroll
                for (int s = 0; s < 2; ++s) {
                    bbuf[nxt][2 * s + 0] = *(const float4*)&Bm[(size_t)(k1 + kr2 + 32 * s) * 4096 + n0 + 4 * nq];
                    bbuf[nxt][2 * s + 1] = *(const float4*)&Bm[(size_t)(k1 + kr2 + 1 + 32 * s) * 4096 + n0 + 4 * nq];
                }
            }
        }
        // stage B (hi only) from the already-loaded buffer
        if (TB) {
#pragma unroll
            for (int s = 0; s < 4; ++s) {
                int off = 4 * sj + 16 * s;
                int idx = sr * 64 + (((off >> 3) ^ (sr & 7)) * 8 + (off & 7));
                float fb[4] = {bbuf[cur][s].x, bbuf[cur][s].y, bbuf[cur][s].z, bbuf[cur][s].w};
                ushort4 h4;
                ushort* hp = (ushort*)&h4;
#pragma unroll
                for (int i = 0; i < 4; ++i) hp[i] = f2bf(fb[i]);
                *(ushort4*)&sh.g.Bh[idx] = h4;
            }
        } else {
#pragma unroll
            for (int s = 0; s < 2; ++s) {
                int k = kr2 + 32 * s;
                float fa[4] = {bbuf[cur][2 * s].x, bbuf[cur][2 * s].y, bbuf[cur][2 * s].z, bbuf[cur][2 * s].w};
                float fb[4] = {bbuf[cur][2 * s + 1].x, bbuf[cur][2 * s + 1].y, bbuf[cur][2 * s + 1].z, bbuf[cur][2 * s + 1].w};
#pragma unroll
                for (int i = 0; i < 4; ++i) {
                    int n = 4 * nq + i;
                    int idx = n * 64 + (((k >> 3) ^ (n & 7)) * 8 + (k & 7));
                    ushort2 hp2;
                    hp2.x = f2bf(fa[i]);
                    hp2.y = f2bf(fb[i]);
                    *(ushort2*)&sh.g.Bh[idx] = hp2;
                }
            }
        }
        // stage A (hi + lo)
#pragma unroll
        for (int s = 0; s < 4; ++s) {
            int off = 4 * sj + 16 * s;
            int idx = sr * 64 + (((off >> 3) ^ (sr & 7)) * 8 + (off & 7));
            float fa[4] = {av[s].x, av[s].y, av[s].z, av[s].w};
            ushort4 h4, l4;
            ushort* hp = (ushort*)&h4; ushort* lp = (ushort*)&l4;
#pragma unroll
            for (int i = 0; i < 4; ++i) {
                ushort h = f2bf(fa[i]);
                hp[i] = h; lp[i] = f2bf(fa[i] - bf2f(h));
            }
            *(ushort4*)&sh.g.Ah[idx] = h4;
            *(ushort4*)&sh.g.Al[idx] = l4;
        }
        __syncthreads();
#pragma unroll
        for (int s16 = 0; s16 < 4; ++s16) {
            int gk = 2 * s16 + lk;
            int ai = am * 64 + ((gk ^ (am & 7)) * 8);
            int bi = bn * 64 + ((gk ^ (bn & 7)) * 8);
            short8 ah = *(const short8*)&sh.g.Ah[ai];
            short8 al = *(const short8*)&sh.g.Al[ai];
            short8 bh = *(const short8*)&sh.g.Bh[bi];
            acc = mfma_bf16(ah, bh, acc);
            acc = mfma_bf16(al, bh, acc);
        }
    }
    const int colg = n0 + tn * 32 + (l & 31);
#pragma unroll
    for (int r = 0; r < 16; ++r) {
        int row = (r & 3) + 8 * (r >> 2) + 4 * lk + tm * 32;
        atomicAdd(&C[row * 4096 + colg], acc[r]);
    }
}

// ---------------- solve: T += a^(2^j) * (G_j @ T), j=0..4 -------------------
__global__ __launch_bounds__(256) void solve_kernel(const float* __restrict__ W,
                                                    const float* __restrict__ Gp,
                                                    const float* __restrict__ lam,
                                                    const float* __restrict__ gammap,
                                                    float* __restrict__ Y) {
    __shared__ float Gs[64][68];
    __shared__ float T[64][17];
    const int t = threadIdx.x;
    const int c0 = blockIdx.x * 16;
    for (int e = t; e < 1024; e += 256)
        T[e >> 4][e & 15] = W[(e >> 4) * 4096 + c0 + (e & 15)];
    const int tx = t & 15;
    const int r4 = (t >> 4) * 4;
    const float a = gammap[0] * lam[c0 + tx];
    float s = a;
    for (int j = 0; j < 5; ++j) {
        __syncthreads();
        for (int e = t; e < 4096; e += 256) Gs[e >> 6][e & 63] = Gp[j * 4096 + e];
        __syncthreads();
        float u0 = 0.f, u1 = 0.f, u2 = 0.f, u3 = 0.f;
#pragma unroll 8
        for (int k = 0; k < 64; ++k) {
            const float tv = T[k][tx];
            const float4 g = *(const float4*)&Gs[k][r4];
            u0 += g.x * tv; u1 += g.y * tv; u2 += g.z * tv; u3 += g.w * tv;
        }
        __syncthreads();
        T[r4 + 0][tx] += s * u0;
        T[r4 + 1][tx] += s * u1;
        T[r4 + 2][tx] += s * u2;
        T[r4 + 3][tx] += s * u3;
        s = s * s;
    }
    __syncthreads();
    for (int e = t; e < 1024; e += 256)
        Y[(e >> 4) * 4096 + c0 + (e & 15)] = T[e >> 4][e & 15];
}

extern "C" void kernel_launch(void* const* d_in, const int* in_sizes, int n_in,
                              void* d_out, int out_size, void* d_ws, size_t ws_size,
                              hipStream_t stream) {
    const float* X     = (const float*)d_in[0];
    const float* F     = (const float*)d_in[1];
    const float* Qs    = (const float*)d_in[2];
    const float* lam   = (const float*)d_in[3];
    const float* gamma = (const float*)d_in[4];
    float* Z = (float*)d_out;

    float* W  = (float*)d_ws;   // 1 MB
    float* Y  = W + Mdim * Ndim;
    float* Gp = Y + Mdim * Ndim;

    init_kernel<<<512, 256, 0, stream>>>(W, Z);
    gemm_kernel<false, true><<<64 * KSPLIT + 1, 256, 0, stream>>>(X, Qs, W, F, Gp);
    solve_kernel<<<Ndim / 16, 256, 0, stream>>>(W, Gp, lam, gamma, Y);
    gemm_kernel<true, false><<<64 * KSPLIT, 256, 0, stream>>>(Y, Qs, Z, nullptr, nullptr);
}